// Round 9
// baseline (3322.572 us; speedup 1.0000x reference)
//
#include <hip/hip_runtime.h>

#define B_ 8
#define L_ 2048
#define D_ 64
#define K_ 40
#define NU_ 32
#define T_ 2047          // L-1
#define NCHAIN 6560      // 8 * sum_{r<40}(r+1)
#define NBALLAST 256

// ---- workspace layout (floats) ----
#define XT_OFF   0
#define XT_SZ    (B_*L_*NU_)             // 524288
#define HTH_OFF  (XT_OFF + XT_SZ)
#define HTH_SZ   (B_*K_*NU_*NU_)         // 327680
#define HTX_OFF  (HTH_OFF + HTH_SZ)
#define HTX_SZ   (B_*K_*NU_*D_)          // 655360
#define SH_OFF   (HTX_OFF + HTX_SZ)
#define SH_SZ    (B_*K_*NU_)             // 10240
#define SX_OFF   (SH_OFF + SH_SZ)
#define SX_SZ    (B_*K_)                 // 320
#define DONE_OFF (SX_OFF + SX_SZ)
#define DONE_SZ  8
#define ZERO_SZ  (HTH_SZ + HTX_SZ + SH_SZ + SX_SZ + DONE_SZ)

#if __has_builtin(__builtin_amdgcn_exp2f)
#define EXP2F(x) __builtin_amdgcn_exp2f(x)
#else
#define EXP2F(x) __expf((x)*0.6931471805599453f)
#endif
#if __has_builtin(__builtin_amdgcn_rcpf)
#define RCPF(x) __builtin_amdgcn_rcpf(x)
#else
#define RCPF(x) (1.0f/(x))
#endif

#define R32(F) F(0) F(1) F(2) F(3) F(4) F(5) F(6) F(7) F(8) F(9) F(10) F(11) \
               F(12) F(13) F(14) F(15) F(16) F(17) F(18) F(19) F(20) F(21) F(22) \
               F(23) F(24) F(25) F(26) F(27) F(28) F(29) F(30) F(31)

// ================= K1: xt = x @ W_in  (B*L rows, 64 -> 32) =================
__global__ __launch_bounds__(256) void k1_xt(const float* __restrict__ x,
                                             const float* __restrict__ Win,
                                             float* __restrict__ xt)
{
    __shared__ float Ws[D_*NU_];
    for (int i = threadIdx.x; i < D_*NU_; i += 256) Ws[i] = Win[i];
    __syncthreads();
    int gid = blockIdx.x*256 + threadIdx.x;
    int m   = gid & 31;
    int row = gid >> 5;
    const float4* xr = (const float4*)(x + (size_t)row * 64);
    float s = 0.f;
#pragma unroll
    for (int q = 0; q < 16; ++q) {
        float4 v = xr[q];
        s = fmaf(v.x, Ws[(q*4+0)*32+m], s);
        s = fmaf(v.y, Ws[(q*4+1)*32+m], s);
        s = fmaf(v.z, Ws[(q*4+2)*32+m], s);
        s = fmaf(v.w, Ws[(q*4+3)*32+m], s);
    }
    xt[gid] = s;
}

// ================= K2F: recurrence with fused HtH/HtX accumulation ==========
// One wave per chain (b, r, c); chains ordered LONGEST-FIRST (r ascending) so
// all long chains are co-resident in the first dispatch fill.
// Lane roles: m = l&31 owns recurrence output m (halves redundant);
//             lane l = d owns HtX column d (all 64 distinct).
// Per step: 32 bpermute broadcasts of h(t_prev); rec dot; accH[n] += h_prev_self
// *bp[n]; accX[n] += x_prev*bp[n] -- both OFF the serial h-chain. Results merged
// by atomicAdd at chain end. No hh matrix, no separate GEMM kernel.
// Ballast blocks (dispatched last) burn VALU until all r==0 chains signal done,
// to hold DPM clocks up through the low-occupancy tail.
#define BPV(N) __int_as_float(__builtin_amdgcn_ds_bpermute(zbase + ((N)<<2), hb))

#define DOA(N, ACC) { float bpv = BPV(N); \
    ACC    = fmaf(w##N, bpv, ACC); \
    aH##N  = fmaf(hp,   bpv, aH##N); \
    aX##N  = fmaf(xlag, bpv, aX##N); }

#define STEP(XTV, XXV) { \
    float hp = __int_as_float(hb); \
    float a0 = XTV, a1 = 0.f, a2 = 0.f, a3 = 0.f; \
    DOA(0,a0)  DOA(1,a1)  DOA(2,a2)  DOA(3,a3) \
    DOA(4,a0)  DOA(5,a1)  DOA(6,a2)  DOA(7,a3) \
    DOA(8,a0)  DOA(9,a1)  DOA(10,a2) DOA(11,a3) \
    DOA(12,a0) DOA(13,a1) DOA(14,a2) DOA(15,a3) \
    DOA(16,a0) DOA(17,a1) DOA(18,a2) DOA(19,a3) \
    DOA(20,a0) DOA(21,a1) DOA(22,a2) DOA(23,a3) \
    DOA(24,a0) DOA(25,a1) DOA(26,a2) DOA(27,a3) \
    DOA(28,a0) DOA(29,a1) DOA(30,a2) DOA(31,a3) \
    shacc += hp; sxacc += xlag; \
    float sdot = (a0 + a1) + (a2 + a3); \
    float ex = EXP2F(sdot * 2.8853900817779268f); \
    float hn = fmaf(-2.f, RCPF(ex + 1.f), 1.f); \
    hb = __float_as_int(hn); \
    xlag = XXV; }

#define MINT(tt) ((tt) > (L_-1) ? (L_-1) : (tt))

#define STAGE(XT, XX) { \
    XT##0 = xtb[(size_t)MINT(tstage + 0*st)*NU_]; \
    XT##1 = xtb[(size_t)MINT(tstage + 1*st)*NU_]; \
    XT##2 = xtb[(size_t)MINT(tstage + 2*st)*NU_]; \
    XT##3 = xtb[(size_t)MINT(tstage + 3*st)*NU_]; \
    XT##4 = xtb[(size_t)MINT(tstage + 4*st)*NU_]; \
    XT##5 = xtb[(size_t)MINT(tstage + 5*st)*NU_]; \
    XT##6 = xtb[(size_t)MINT(tstage + 6*st)*NU_]; \
    XT##7 = xtb[(size_t)MINT(tstage + 7*st)*NU_]; \
    XX##0 = xcb[(size_t)MINT(tstage + 0*st + roff)*D_]; \
    XX##1 = xcb[(size_t)MINT(tstage + 1*st + roff)*D_]; \
    XX##2 = xcb[(size_t)MINT(tstage + 2*st + roff)*D_]; \
    XX##3 = xcb[(size_t)MINT(tstage + 3*st + roff)*D_]; \
    XX##4 = xcb[(size_t)MINT(tstage + 4*st + roff)*D_]; \
    XX##5 = xcb[(size_t)MINT(tstage + 5*st + roff)*D_]; \
    XX##6 = xcb[(size_t)MINT(tstage + 6*st + roff)*D_]; \
    XX##7 = xcb[(size_t)MINT(tstage + 7*st + roff)*D_]; \
    tstage += 8*st; }

#define CHUNK(XTc, XXc, XTn, XXn) { \
    STAGE(XTn, XXn) \
    STEP(XTc##0, XXc##0) STEP(XTc##1, XXc##1) STEP(XTc##2, XXc##2) STEP(XTc##3, XXc##3) \
    STEP(XTc##4, XXc##4) STEP(XTc##5, XXc##5) STEP(XTc##6, XXc##6) STEP(XTc##7, XXc##7) }

#define D8(P) float P##0,P##1,P##2,P##3,P##4,P##5,P##6,P##7;

__global__ __launch_bounds__(64, 2) void k2f(const float* __restrict__ ws_xt,
                                             const float* __restrict__ Wres,
                                             const float* __restrict__ radii,
                                             const float* __restrict__ x,
                                             float* __restrict__ htH,
                                             float* __restrict__ htX,
                                             float* __restrict__ sH,
                                             float* __restrict__ sX,
                                             int*   __restrict__ done)
{
    const int l = threadIdx.x;

    if (blockIdx.x >= NCHAIN) {
        // ---------------- ballast: keep DPM clocks up through the tail ------
        float f0 = (float)l + 1.f, f1 = f0*1.5f, f2 = f0*2.5f, f3 = f0*3.5f;
        int guard = 1 << 17;
        while (__hip_atomic_load(done, __ATOMIC_RELAXED,
                                 __HIP_MEMORY_SCOPE_AGENT) < B_ && --guard) {
#pragma unroll
            for (int i = 0; i < 64; ++i) {
                f0 = fmaf(f0, 1.0000001f, 1e-9f);
                f1 = fmaf(f1, 1.0000001f, 1e-9f);
                f2 = fmaf(f2, 1.0000001f, 1e-9f);
                f3 = fmaf(f3, 1.0000001f, 1e-9f);
            }
            asm volatile("" :: "v"(f0), "v"(f1), "v"(f2), "v"(f3));
        }
        return;
    }

    // ---------------- producer: one chain ----------------
    const int m = l & 31;
    // longest-first mapping: chains of reservoir r occupy a block of 8*(r+1)
    int g = blockIdx.x;
    int r = 0, cum = 8;
    while (g >= cum) { ++r; cum += 8*(r+1); }
    const int local = g - (cum - 8*(r+1));
    const int b = local / (r+1);
    const int c = local % (r+1);
    const int st   = r + 1;
    const int roff = r + 1;
    const float rad = radii[r];

    if (r == 0)      __builtin_amdgcn_s_setprio(3);
    else if (r <= 2) __builtin_amdgcn_s_setprio(2);
    else if (r <= 6) __builtin_amdgcn_s_setprio(1);

    const float* Wp = Wres + r*1024 + m;
    #define DECL_W(N) float w##N = Wp[(N)*NU_] * rad;
    R32(DECL_W)
    #define DECL_AH(N) float aH##N = 0.f;
    R32(DECL_AH)
    #define DECL_AX(N) float aX##N = 0.f;
    R32(DECL_AX)

    const float* xtb = ws_xt + (size_t)b * L_ * NU_ + m;  // xt column m, idx t*32
    const float* xcb = x     + (size_t)b * L_ * D_  + l;  // x  column l, idx t*64

    int zbase = 0;
    asm volatile("" : "+v"(zbase));      // keep bpermute base in a VGPR

    const int nsteps = (T_ - 1 - r - c) / st + 1;   // accumulate only t <= T-1-r
    const int nfull  = nsteps >> 3;
    const int tail   = nsteps & 7;

    D8(ta) D8(tb) D8(xa) D8(xb)
    int tstage = c;
    STAGE(ta, xa)                         // chunk 0

    int   hb    = 0;                      // h = 0 initial state
    float xlag  = 0.f;                    // x paired with h_prev (0 at j=0: h=0)
    float shacc = 0.f, sxacc = 0.f;

    int c2 = 0;
    for (; c2 + 2 <= nfull; c2 += 2) {
        CHUNK(ta, xa, tb, xb)
        CHUNK(tb, xb, ta, xa)
    }
    if (c2 < nfull) { CHUNK(ta, xa, tb, xb) }

    // tail (< 8 steps): direct loads, latency exposed but tiny
    int tcur = c + nfull*8*st;
    for (int j = 0; j < tail; ++j) {
        float xtv = xtb[(size_t)tcur * NU_];
        float xxv = xcb[(size_t)(tcur + roff) * D_];
        STEP(xtv, xxv)
        tcur += st;
    }

    // epilogue: accumulate the final h (loop accumulates h_prev only)
    {
        float hp = __int_as_float(hb);
        #define FIN(N) { float bpv = BPV(N); \
            aH##N = fmaf(hp, bpv, aH##N); aX##N = fmaf(xlag, bpv, aX##N); }
        R32(FIN)
        shacc += hp; sxacc += xlag;
    }

    // merge: atomics (addresses coalesced across lanes)
    const int bk = b*K_ + r;
    float* pX = htX + (size_t)bk * (NU_*D_) + l;
    #define ATX(N) atomicAdd(pX + (N)*D_, aX##N);
    R32(ATX)
    if (l < NU_) {
        float* pH = htH + (size_t)bk * (NU_*NU_) + m;
        #define ATH(N) atomicAdd(pH + (N)*NU_, aH##N);
        R32(ATH)
        atomicAdd(&sH[bk*NU_ + m], shacc);
    }
#pragma unroll
    for (int off = 32; off > 0; off >>= 1) sxacc += __shfl_xor(sxacc, off);
    if (l == 0) {
        atomicAdd(&sX[bk], sxacc);
        if (r == 0)
            __hip_atomic_fetch_add(done, 1, __ATOMIC_RELAXED,
                                   __HIP_MEMORY_SCOPE_AGENT);
    }
}

// ================= K4: Cholesky solve + features + f_norms =================
__global__ __launch_bounds__(64) void k4_solve(const float* __restrict__ htH,
                                               const float* __restrict__ htX,
                                               const float* __restrict__ sH,
                                               const float* __restrict__ sX,
                                               float* __restrict__ dout)
{
    const int k  = blockIdx.x;
    const int b  = blockIdx.y;
    const int bk = b*K_ + k;
    const int l  = threadIdx.x;
    __shared__ float As[32][33];
#pragma unroll
    for (int i = 0; i < 16; ++i) {
        int idx = i*64 + l;
        int row = idx >> 5, col = idx & 31;
        As[row][col] = htH[(size_t)bk*1024 + idx] + ((row == col) ? 1.0f : 0.0f);
    }
    __syncthreads();
    for (int j = 0; j < 32; ++j) {
        float d   = sqrtf(As[j][j]);
        float inv = 1.0f / d;
        if (l == j) As[j][j] = d;
        if (l < 32 && l > j) As[l][j] *= inv;
        __syncthreads();
        if (l < 32 && l > j) {
            float lij = As[l][j];
            for (int c = j+1; c <= l; ++c)
                As[l][c] -= lij * As[c][j];
        }
        __syncthreads();
    }
    float y[32];
#pragma unroll
    for (int i = 0; i < 32; ++i)
        y[i] = htX[(size_t)bk*2048 + i*64 + l];
#pragma unroll
    for (int i = 0; i < 32; ++i) {
        float v = y[i];
#pragma unroll
        for (int j = 0; j < i; ++j) v = fmaf(-As[i][j], y[j], v);
        y[i] = v / As[i][i];
    }
#pragma unroll
    for (int i = 31; i >= 0; --i) {
        float v = y[i];
#pragma unroll
        for (int j = i+1; j < 32; ++j) v = fmaf(-As[j][i], y[j], v);
        y[i] = v / As[i][i];
    }
    float* fout = dout + (size_t)bk * NU_ * D_;
#pragma unroll
    for (int n = 0; n < 32; ++n) fout[n*64 + l] = y[n];
    const float* sh = sH + bk*32;
    float part = 0.f;
#pragma unroll
    for (int n = 0; n < 32; ++n) part = fmaf(sh[n], y[n], part);
#pragma unroll
    for (int off = 32; off > 0; off >>= 1) part += __shfl_xor(part, off);
    if (l == 0) atomicAdd(dout + (size_t)(B_*K_*NU_*D_) + k, part - sX[bk]);
}

// ============================================================================
extern "C" void kernel_launch(void* const* d_in, const int* in_sizes, int n_in,
                              void* d_out, int out_size, void* d_ws, size_t ws_size,
                              hipStream_t stream)
{
    const float* x     = (const float*)d_in[0];
    const float* radii = (const float*)d_in[1];
    const float* Win   = (const float*)d_in[2];
    const float* Wres  = (const float*)d_in[3];
    float* ws  = (float*)d_ws;
    float* xt  = ws + XT_OFF;
    float* htH = ws + HTH_OFF;
    float* htX = ws + HTX_OFF;
    float* sH  = ws + SH_OFF;
    float* sX  = ws + SX_OFF;
    int*   done = (int*)(ws + DONE_OFF);
    float* out = (float*)d_out;

    hipMemsetAsync(htH, 0, (size_t)ZERO_SZ*sizeof(float), stream);
    hipMemsetAsync(out + (size_t)B_*K_*NU_*D_, 0, K_*sizeof(float), stream);

    k1_xt<<<(B_*L_*NU_)/256, 256, 0, stream>>>(x, Win, xt);
    k2f  <<<NCHAIN + NBALLAST, 64, 0, stream>>>(xt, Wres, radii, x,
                                                htH, htX, sH, sX, done);
    k4_solve<<<dim3(K_, B_), 64, 0, stream>>>(htH, htX, sH, sX, out);
}

// Round 11
// 1081.755 us; speedup vs baseline: 3.0715x; 3.0715x over previous
//
#include <hip/hip_runtime.h>

#define B_ 8
#define L_ 2048
#define D_ 64
#define K_ 40
#define NU_ 32
#define T_ 2047          // L-1
#define NCHAIN 6560      // 8 * sum_{r<40}(r+1)
#define NBALLAST 256

// ---- workspace layout (floats) ----
#define XT_OFF   0
#define XT_SZ    (B_*L_*NU_)             // 524288
#define HTH_OFF  (XT_OFF + XT_SZ)
#define HTH_SZ   (B_*K_*NU_*NU_)         // 327680
#define HTX_OFF  (HTH_OFF + HTH_SZ)
#define HTX_SZ   (B_*K_*NU_*D_)          // 655360
#define SH_OFF   (HTX_OFF + HTX_SZ)
#define SH_SZ    (B_*K_*NU_)             // 10240
#define SX_OFF   (SH_OFF + SH_SZ)
#define SX_SZ    (B_*K_)                 // 320
#define DONE_OFF (SX_OFF + SX_SZ)
#define DONE_SZ  8
#define ZERO_SZ  (HTH_SZ + HTX_SZ + SH_SZ + SX_SZ + DONE_SZ)

#if __has_builtin(__builtin_amdgcn_exp2f)
#define EXP2F(x) __builtin_amdgcn_exp2f(x)
#else
#define EXP2F(x) __expf((x)*0.6931471805599453f)
#endif
#if __has_builtin(__builtin_amdgcn_rcpf)
#define RCPF(x) __builtin_amdgcn_rcpf(x)
#else
#define RCPF(x) (1.0f/(x))
#endif

#define R32(F) F(0) F(1) F(2) F(3) F(4) F(5) F(6) F(7) F(8) F(9) F(10) F(11) \
               F(12) F(13) F(14) F(15) F(16) F(17) F(18) F(19) F(20) F(21) F(22) \
               F(23) F(24) F(25) F(26) F(27) F(28) F(29) F(30) F(31)

// ================= K1: xt = x @ W_in  (B*L rows, 64 -> 32) =================
__global__ __launch_bounds__(256) void k1_xt(const float* __restrict__ x,
                                             const float* __restrict__ Win,
                                             float* __restrict__ xt)
{
    __shared__ float Ws[D_*NU_];
    for (int i = threadIdx.x; i < D_*NU_; i += 256) Ws[i] = Win[i];
    __syncthreads();
    int gid = blockIdx.x*256 + threadIdx.x;
    int m   = gid & 31;
    int row = gid >> 5;
    const float4* xr = (const float4*)(x + (size_t)row * 64);
    float s = 0.f;
#pragma unroll
    for (int q = 0; q < 16; ++q) {
        float4 v = xr[q];
        s = fmaf(v.x, Ws[(q*4+0)*32+m], s);
        s = fmaf(v.y, Ws[(q*4+1)*32+m], s);
        s = fmaf(v.z, Ws[(q*4+2)*32+m], s);
        s = fmaf(v.w, Ws[(q*4+3)*32+m], s);
    }
    xt[gid] = s;
}

// ================= K2F: recurrence + fused HtH/HtX, register-overlaid =======
// One wave per chain (b,r,c), longest-first. PER-LANE REGISTER OVERLAY:
//   w0..31 : lanes<32 = W column m (recurrence weights, NEVER changed there:
//            update adds hmask*bpv with hmask==0 in lower lanes);
//            lanes>=32 = aH accumulators for HtH column (l-32).
//   AX0..31: all lanes = HtX accumulators for column d=l.
// hself = bpermute(h, (l&31)*4) gives each lane h[m] off the serial chain.
// Upper-lane recurrence values are garbage-but-finite and never read
// (bpermute indices < 32 read lanes<32 only). ~111 VGPRs needed.
// __launch_bounds__(64,1): loosest register cap (512) -- round 9's (64,2)
// still clamped to 128 and spilled (3 GB scratch traffic, 3.4 ms).
// Ballast blocks hold DPM clocks up through the r=0 tail (clock-theory test).
#define BPV(N) __int_as_float(__builtin_amdgcn_ds_bpermute(zbase + ((N)<<2), hb))

#define DOA(N, ACC) { float bpv = BPV(N); \
    ACC   = fmaf(w##N,  bpv, ACC); \
    w##N  = fmaf(hmask, bpv, w##N); \
    AX##N = fmaf(xlag,  bpv, AX##N); }

#define STEP(XTV, XXV) { \
    float hself = __int_as_float(__builtin_amdgcn_ds_bpermute(selfb, hb)); \
    float hmask = hself * umask; \
    float a0 = XTV, a1 = 0.f, a2 = 0.f, a3 = 0.f; \
    DOA(0,a0)  DOA(1,a1)  DOA(2,a2)  DOA(3,a3) \
    DOA(4,a0)  DOA(5,a1)  DOA(6,a2)  DOA(7,a3) \
    DOA(8,a0)  DOA(9,a1)  DOA(10,a2) DOA(11,a3) \
    DOA(12,a0) DOA(13,a1) DOA(14,a2) DOA(15,a3) \
    DOA(16,a0) DOA(17,a1) DOA(18,a2) DOA(19,a3) \
    DOA(20,a0) DOA(21,a1) DOA(22,a2) DOA(23,a3) \
    DOA(24,a0) DOA(25,a1) DOA(26,a2) DOA(27,a3) \
    DOA(28,a0) DOA(29,a1) DOA(30,a2) DOA(31,a3) \
    shacc += hself; sxacc += xlag; \
    float sdot = (a0 + a1) + (a2 + a3); \
    float ex = EXP2F(sdot * 2.8853900817779268f); \
    float hn = fmaf(-2.f, RCPF(ex + 1.f), 1.f); \
    hb = __float_as_int(hn); \
    xlag = XXV; }

#define MINT(tt) ((tt) > (L_-1) ? (L_-1) : (tt))

#define STAGE(XT, XX) { \
    XT##0 = xtb[(size_t)MINT(tstage + 0*st)*NU_]; \
    XT##1 = xtb[(size_t)MINT(tstage + 1*st)*NU_]; \
    XT##2 = xtb[(size_t)MINT(tstage + 2*st)*NU_]; \
    XT##3 = xtb[(size_t)MINT(tstage + 3*st)*NU_]; \
    XT##4 = xtb[(size_t)MINT(tstage + 4*st)*NU_]; \
    XT##5 = xtb[(size_t)MINT(tstage + 5*st)*NU_]; \
    XT##6 = xtb[(size_t)MINT(tstage + 6*st)*NU_]; \
    XT##7 = xtb[(size_t)MINT(tstage + 7*st)*NU_]; \
    XX##0 = xcb[(size_t)MINT(tstage + 0*st + roff)*D_]; \
    XX##1 = xcb[(size_t)MINT(tstage + 1*st + roff)*D_]; \
    XX##2 = xcb[(size_t)MINT(tstage + 2*st + roff)*D_]; \
    XX##3 = xcb[(size_t)MINT(tstage + 3*st + roff)*D_]; \
    XX##4 = xcb[(size_t)MINT(tstage + 4*st + roff)*D_]; \
    XX##5 = xcb[(size_t)MINT(tstage + 5*st + roff)*D_]; \
    XX##6 = xcb[(size_t)MINT(tstage + 6*st + roff)*D_]; \
    XX##7 = xcb[(size_t)MINT(tstage + 7*st + roff)*D_]; \
    tstage += 8*st; }

#define CHUNK(XTc, XXc, XTn, XXn) { \
    STAGE(XTn, XXn) \
    STEP(XTc##0, XXc##0) STEP(XTc##1, XXc##1) STEP(XTc##2, XXc##2) STEP(XTc##3, XXc##3) \
    STEP(XTc##4, XXc##4) STEP(XTc##5, XXc##5) STEP(XTc##6, XXc##6) STEP(XTc##7, XXc##7) }

#define D8(P) float P##0,P##1,P##2,P##3,P##4,P##5,P##6,P##7;

__global__ __launch_bounds__(64, 1) void k2f(const float* __restrict__ ws_xt,
                                             const float* __restrict__ Wres,
                                             const float* __restrict__ radii,
                                             const float* __restrict__ x,
                                             float* __restrict__ htH,
                                             float* __restrict__ htX,
                                             float* __restrict__ sH,
                                             float* __restrict__ sX,
                                             int*   __restrict__ done)
{
    const int l = threadIdx.x;

    if (blockIdx.x >= NCHAIN) {
        // ---------------- ballast: keep DPM clocks up through the tail ------
        float f0 = (float)l + 1.f, f1 = f0*1.5f, f2 = f0*2.5f, f3 = f0*3.5f;
        int guard = 1 << 17;
        while (__hip_atomic_load(done, __ATOMIC_RELAXED,
                                 __HIP_MEMORY_SCOPE_AGENT) < B_ && --guard) {
#pragma unroll
            for (int i = 0; i < 64; ++i) {
                f0 = fmaf(f0, 1.0000001f, 1e-9f);
                f1 = fmaf(f1, 1.0000001f, 1e-9f);
                f2 = fmaf(f2, 1.0000001f, 1e-9f);
                f3 = fmaf(f3, 1.0000001f, 1e-9f);
            }
            asm volatile("" :: "v"(f0), "v"(f1), "v"(f2), "v"(f3));
        }
        return;
    }

    // ---------------- producer: one chain ----------------
    const int m = l & 31;
    const float umask = (l >= 32) ? 1.0f : 0.0f;
    const int selfb = m << 2;
    // longest-first mapping: chains of reservoir r occupy a block of 8*(r+1)
    int g = blockIdx.x;
    int r = 0, cum = 8;
    while (g >= cum) { ++r; cum += 8*(r+1); }
    const int local = g - (cum - 8*(r+1));
    const int b = local / (r+1);
    const int c = local % (r+1);
    const int st   = r + 1;
    const int roff = r + 1;
    const float rad = radii[r];

    if (r == 0)      __builtin_amdgcn_s_setprio(3);
    else if (r <= 2) __builtin_amdgcn_s_setprio(2);
    else if (r <= 6) __builtin_amdgcn_s_setprio(1);

    // lanes<32: w = W column m * rad. lanes>=32: these registers become the
    // aH accumulators -> initialize to 0 there (umask trick keeps them pure).
    const float* Wp = Wres + r*1024 + m;
    const float wsc = (l < 32) ? rad : 0.0f;
    #define DECL_W(N) float w##N = Wp[(N)*NU_] * wsc;
    R32(DECL_W)
    #define DECL_AX(N) float AX##N = 0.f;
    R32(DECL_AX)

    const float* xtb = ws_xt + (size_t)b * L_ * NU_ + m;  // xt column m
    const float* xcb = x     + (size_t)b * L_ * D_  + l;  // x  column l

    int zbase = 0;
    asm volatile("" : "+v"(zbase));      // keep bpermute base in a VGPR

    const int nsteps = (T_ - 1 - r - c) / st + 1;   // t <= T-1-r only
    const int nfull  = nsteps >> 3;
    const int tail   = nsteps & 7;

    D8(ta) D8(tb) D8(xa) D8(xb)
    int tstage = c;
    STAGE(ta, xa)                         // chunk 0

    int   hb    = 0;                      // h = 0 initial state
    float xlag  = 0.f;                    // x paired with h_prev
    float shacc = 0.f, sxacc = 0.f;

    int c2 = 0;
    for (; c2 + 2 <= nfull; c2 += 2) {
        CHUNK(ta, xa, tb, xb)
        CHUNK(tb, xb, ta, xa)
    }
    if (c2 < nfull) { CHUNK(ta, xa, tb, xb) }

    // tail (< 8 steps): direct loads
    int tcur = c + nfull*8*st;
    for (int j = 0; j < tail; ++j) {
        float xtv = xtb[(size_t)tcur * NU_];
        float xxv = xcb[(size_t)(tcur + roff) * D_];
        STEP(xtv, xxv)
        tcur += st;
    }

    // epilogue: accumulate the final h
    {
        float hself = __int_as_float(__builtin_amdgcn_ds_bpermute(selfb, hb));
        float hmask = hself * umask;
        #define FIN(N) { float bpv = BPV(N); \
            w##N  = fmaf(hmask, bpv, w##N); \
            AX##N = fmaf(xlag,  bpv, AX##N); }
        R32(FIN)
        shacc += hself; sxacc += xlag;
    }

    // merge
    const int bk = b*K_ + r;
    float* pX = htX + (size_t)bk * (NU_*D_) + l;
    #define ATX(N) atomicAdd(pX + (N)*D_, AX##N);
    R32(ATX)
    if (l >= 32) {          // upper lanes hold aH column (l-32)
        float* pH = htH + (size_t)bk * (NU_*NU_) + (l - 32);
        #define ATH(N) atomicAdd(pH + (N)*NU_, w##N);
        R32(ATH)
    } else {
        atomicAdd(&sH[bk*NU_ + m], shacc);
    }
#pragma unroll
    for (int off = 32; off > 0; off >>= 1) sxacc += __shfl_xor(sxacc, off);
    if (l == 0) {
        atomicAdd(&sX[bk], sxacc);
        if (r == 0)
            __hip_atomic_fetch_add(done, 1, __ATOMIC_RELAXED,
                                   __HIP_MEMORY_SCOPE_AGENT);
    }
}

// ================= K4: Cholesky solve + features + f_norms =================
__global__ __launch_bounds__(64) void k4_solve(const float* __restrict__ htH,
                                               const float* __restrict__ htX,
                                               const float* __restrict__ sH,
                                               const float* __restrict__ sX,
                                               float* __restrict__ dout)
{
    const int k  = blockIdx.x;
    const int b  = blockIdx.y;
    const int bk = b*K_ + k;
    const int l  = threadIdx.x;
    __shared__ float As[32][33];
#pragma unroll
    for (int i = 0; i < 16; ++i) {
        int idx = i*64 + l;
        int row = idx >> 5, col = idx & 31;
        As[row][col] = htH[(size_t)bk*1024 + idx] + ((row == col) ? 1.0f : 0.0f);
    }
    __syncthreads();
    for (int j = 0; j < 32; ++j) {
        float d   = sqrtf(As[j][j]);
        float inv = 1.0f / d;
        if (l == j) As[j][j] = d;
        if (l < 32 && l > j) As[l][j] *= inv;
        __syncthreads();
        if (l < 32 && l > j) {
            float lij = As[l][j];
            for (int c = j+1; c <= l; ++c)
                As[l][c] -= lij * As[c][j];
        }
        __syncthreads();
    }
    float y[32];
#pragma unroll
    for (int i = 0; i < 32; ++i)
        y[i] = htX[(size_t)bk*2048 + i*64 + l];
#pragma unroll
    for (int i = 0; i < 32; ++i) {
        float v = y[i];
#pragma unroll
        for (int j = 0; j < i; ++j) v = fmaf(-As[i][j], y[j], v);
        y[i] = v / As[i][i];
    }
#pragma unroll
    for (int i = 31; i >= 0; --i) {
        float v = y[i];
#pragma unroll
        for (int j = i+1; j < 32; ++j) v = fmaf(-As[j][i], y[j], v);
        y[i] = v / As[i][i];
    }
    float* fout = dout + (size_t)bk * NU_ * D_;
#pragma unroll
    for (int n = 0; n < 32; ++n) fout[n*64 + l] = y[n];
    const float* sh = sH + bk*32;
    float part = 0.f;
#pragma unroll
    for (int n = 0; n < 32; ++n) part = fmaf(sh[n], y[n], part);
#pragma unroll
    for (int off = 32; off > 0; off >>= 1) part += __shfl_xor(part, off);
    if (l == 0) atomicAdd(dout + (size_t)(B_*K_*NU_*D_) + k, part - sX[bk]);
}

// ============================================================================
extern "C" void kernel_launch(void* const* d_in, const int* in_sizes, int n_in,
                              void* d_out, int out_size, void* d_ws, size_t ws_size,
                              hipStream_t stream)
{
    const float* x     = (const float*)d_in[0];
    const float* radii = (const float*)d_in[1];
    const float* Win   = (const float*)d_in[2];
    const float* Wres  = (const float*)d_in[3];
    float* ws  = (float*)d_ws;
    float* xt  = ws + XT_OFF;
    float* htH = ws + HTH_OFF;
    float* htX = ws + HTX_OFF;
    float* sH  = ws + SH_OFF;
    float* sX  = ws + SX_OFF;
    int*   done = (int*)(ws + DONE_OFF);
    float* out = (float*)d_out;

    hipMemsetAsync(htH, 0, (size_t)ZERO_SZ*sizeof(float), stream);
    hipMemsetAsync(out + (size_t)B_*K_*NU_*D_, 0, K_*sizeof(float), stream);

    k1_xt<<<(B_*L_*NU_)/256, 256, 0, stream>>>(x, Win, xt);
    k2f  <<<NCHAIN + NBALLAST, 64, 0, stream>>>(xt, Wres, radii, x,
                                                htH, htX, sH, sX, done);
    k4_solve<<<dim3(K_, B_), 64, 0, stream>>>(htH, htX, sH, sX, out);
}